// Round 3
// baseline (753.224 us; speedup 1.0000x reference)
//
#include <hip/hip_runtime.h>
#include <stdint.h>

// Problem constants
#define T_  512
#define V_  512
#define F_  12
#define FP_ 16
#define D_  512
#define H_  8
#define HF_ 96

using half8  = __attribute__((ext_vector_type(8))) _Float16;
using f32x4  = __attribute__((ext_vector_type(4))) float;
using uint4v = __attribute__((ext_vector_type(4))) unsigned int;

// Workspace layout (bytes). Total = 128,974,848 (~123 MB)
#define OFF_TB   (0L)                       // text fp16      [512][512]
#define OFF_VB   (524288L)                  // video fp16     [512][16][512] (F padded, zeros)
#define OFF_WQT  (OFF_VB  + 8388608L)       // WqT fp16       [512][512]  WqT[n][k]=Wq[k][n]
#define OFF_WKT  (OFF_WQT + 524288L)
#define OFF_WVT  (OFF_WKT + 524288L)
#define OFF_WOT  (OFF_WVT + 524288L)
#define OFF_QB   (OFF_WOT + 524288L)        // q fp16 (x0.125)[512][512]
#define OFF_KP   (OFF_QB  + 524288L)        // kproj fp16     [512][16][512]
#define OFF_VP   (OFF_KP  + 8388608L)       // vproj fp16     [512][16][512]
#define OFF_ZT   (OFF_VP  + 8388608L)       // Zt fp16        [512][512][96]  Zt[v][n][h*12+f]
#define OFF_WT   (OFF_ZT  + 50331648L)      // Wt fp16        [512][512][96]  Wt[v][t][h*12+f]

__device__ __forceinline__ unsigned short f2h(float x) {
  _Float16 h = (_Float16)x;
  return __builtin_bit_cast(unsigned short, h);
}

__device__ __forceinline__ void cvt8_store(float4 a, float4 b, unsigned short* dst) {
  unsigned int w0 = f2h(a.x) | ((unsigned int)f2h(a.y) << 16);
  unsigned int w1 = f2h(a.z) | ((unsigned int)f2h(a.w) << 16);
  unsigned int w2 = f2h(b.x) | ((unsigned int)f2h(b.y) << 16);
  unsigned int w3 = f2h(b.z) | ((unsigned int)f2h(b.w) << 16);
  uint4v v = {w0, w1, w2, w3};
  *(uint4v*)dst = v;
}

// ---------------------------------------------------------------------------
// K0: convert inputs to fp16; build transposed fp16 weight copies.
// grid: [0,128) text | [128,2176) video (padded F=16) | [2176,2432) transposes
// ---------------------------------------------------------------------------
__global__ __launch_bounds__(256) void k0_prep(
    const float* __restrict__ text, const float* __restrict__ video,
    const float* __restrict__ Wq, const float* __restrict__ Wk,
    const float* __restrict__ Wv, const float* __restrict__ Wo, char* ws) {
  __shared__ unsigned short tl[64][72];
  int bx = blockIdx.x, tid = threadIdx.x;
  if (bx < 128) {
    unsigned short* tb = (unsigned short*)(ws + OFF_TB);
    long i = ((long)bx * 256 + tid) * 8;
    float4 a = *(const float4*)(text + i);
    float4 b = *(const float4*)(text + i + 4);
    cvt8_store(a, b, tb + i);
  } else if (bx < 2176) {
    unsigned short* vb = (unsigned short*)(ws + OFF_VB);
    long j = ((long)(bx - 128) * 256 + tid) * 8;  // elem idx in [512][16][512]
    int row = (int)(j >> 9);
    int c   = (int)(j & 511);
    int f = row & 15, v = row >> 4;
    if (f < F_) {
      const float* src = video + ((long)(v * F_ + f) << 9) + c;
      float4 a = *(const float4*)src;
      float4 b = *(const float4*)(src + 4);
      cvt8_store(a, b, vb + j);
    } else {
      uint4v z = {0, 0, 0, 0};
      *(uint4v*)(vb + j) = z;
    }
  } else {
    int tix = bx - 2176;
    int w = tix >> 6, tile = tix & 63;
    const float* W = (w == 0) ? Wq : (w == 1) ? Wk : (w == 2) ? Wv : Wo;
    unsigned short* WT = (unsigned short*)(ws +
        ((w == 0) ? OFF_WQT : (w == 1) ? OFF_WKT : (w == 2) ? OFF_WVT : OFF_WOT));
    int r0 = (tile >> 3) * 64, c0 = (tile & 7) * 64;
    int rr = tid >> 4, cc = (tid & 15) * 4;
#pragma unroll
    for (int j2 = 0; j2 < 4; ++j2) {
      int r = rr + j2 * 16;
      float4 a = *(const float4*)(W + (long)(r0 + r) * 512 + c0 + cc);
      tl[cc + 0][r] = f2h(a.x);
      tl[cc + 1][r] = f2h(a.y);
      tl[cc + 2][r] = f2h(a.z);
      tl[cc + 3][r] = f2h(a.w);
    }
    __syncthreads();
    // 256 threads x 16 ushorts = the full 64x64 tile in ONE pass.
    int row_l = tid >> 2, u = (tid & 3) * 16;
    uint4v x0 = *(uint4v*)&tl[row_l][u];
    uint4v x1 = *(uint4v*)&tl[row_l][u + 8];
    unsigned short* dst = WT + (long)(c0 + row_l) * 512 + r0 + u;
    *(uint4v*)dst = x0;
    *(uint4v*)(dst + 8) = x1;
  }
}

// ---------------------------------------------------------------------------
// K1: fused projection GEMMs (fp16 MFMA).  out = (A @ W + b) * scale
// grid = 132 mtiles * 4 ntiles; seg mt<4: q | mt<68: kproj | else: vproj
// tile 128x128, BK=64, 4 waves (2x2 of 64x64)
// ---------------------------------------------------------------------------
__global__ __launch_bounds__(256) void k1_proj(
    char* ws, const float* __restrict__ bq, const float* __restrict__ bk,
    const float* __restrict__ bv) {
  __shared__ unsigned short As[128 * 72];
  __shared__ unsigned short Bs[128 * 72];
  int bx = blockIdx.x, tid = threadIdx.x;
  int nt = bx & 3, mt = bx >> 2;
  const unsigned short* A;
  const unsigned short* BT;
  const float* bias;
  float scale;
  unsigned short* out;
  int m0;
  if (mt < 4) {
    A = (const unsigned short*)(ws + OFF_TB);
    BT = (const unsigned short*)(ws + OFF_WQT);
    bias = bq; scale = 0.125f;
    out = (unsigned short*)(ws + OFF_QB);
    m0 = mt << 7;
  } else if (mt < 68) {
    A = (const unsigned short*)(ws + OFF_VB);
    BT = (const unsigned short*)(ws + OFF_WKT);
    bias = bk; scale = 1.0f;
    out = (unsigned short*)(ws + OFF_KP);
    m0 = (mt - 4) << 7;
  } else {
    A = (const unsigned short*)(ws + OFF_VB);
    BT = (const unsigned short*)(ws + OFF_WVT);
    bias = bv; scale = 1.0f;
    out = (unsigned short*)(ws + OFF_VP);
    m0 = (mt - 68) << 7;
  }
  int n0 = nt << 7;
  int lane = tid & 63, wid = tid >> 6;
  int mw = (wid >> 1) << 6, nw = (wid & 1) << 6;
  int l15 = lane & 15, g = lane >> 4;
  f32x4 acc[4][4];
#pragma unroll
  for (int i = 0; i < 4; i++)
#pragma unroll
    for (int j = 0; j < 4; j++) acc[i][j] = (f32x4){0.f, 0.f, 0.f, 0.f};

  for (int ks = 0; ks < 8; ++ks) {
    __syncthreads();
    // stage A,B [128][64] -> padded [128][72]
#pragma unroll
    for (int j = 0; j < 4; ++j) {
      int flat = (j * 256 + tid) * 8;
      int row = flat >> 6, col = flat & 63;
      uint4v va = *(const uint4v*)(A + (long)(m0 + row) * 512 + ks * 64 + col);
      uint4v vb = *(const uint4v*)(BT + (long)(n0 + row) * 512 + ks * 64 + col);
      *(uint4v*)(As + row * 72 + col) = va;
      *(uint4v*)(Bs + row * 72 + col) = vb;
    }
    __syncthreads();
#pragma unroll
    for (int k2 = 0; k2 < 2; ++k2) {
      half8 a[4], b[4];
#pragma unroll
      for (int i = 0; i < 4; i++) {
        a[i] = *(const half8*)(As + (mw + i * 16 + l15) * 72 + k2 * 32 + (g << 3));
        b[i] = *(const half8*)(Bs + (nw + i * 16 + l15) * 72 + k2 * 32 + (g << 3));
      }
#pragma unroll
      for (int i = 0; i < 4; i++)
#pragma unroll
        for (int j = 0; j < 4; j++)
          acc[i][j] = __builtin_amdgcn_mfma_f32_16x16x32_f16(a[i], b[j], acc[i][j], 0, 0, 0);
    }
  }
#pragma unroll
  for (int j = 0; j < 4; j++) {
    int n = n0 + nw + j * 16 + l15;
    float bsv = bias[n];
#pragma unroll
    for (int i = 0; i < 4; i++) {
      int rbase = m0 + mw + i * 16 + (g << 2);
#pragma unroll
      for (int r = 0; r < 4; r++) {
        float x = (acc[i][j][r] + bsv) * scale;
        out[(long)(rbase + r) * 512 + n] = f2h(x);
      }
    }
  }
}

// ---------------------------------------------------------------------------
// K2: Zt[v][n][h*12+f] = sum_d vproj[v,f,h*64+d] * Wo[h*64+d, n]
// per (v,h): C[n][f] = WoT-rows x vproj-f-rows  (16x16x32 MFMA, K=64)
// grid = 512 v * 4 ntiles; wave covers 32 n-rows
// ---------------------------------------------------------------------------
__global__ __launch_bounds__(256) void k2_z(char* ws) {
  int bx = blockIdx.x, tid = threadIdx.x;
  int v = bx >> 2, nt = bx & 3;
  const unsigned short* WoT = (const unsigned short*)(ws + OFF_WOT);
  const unsigned short* vp = (const unsigned short*)(ws + OFF_VP);
  unsigned short* Zt = (unsigned short*)(ws + OFF_ZT);
  int lane = tid & 63, wid = tid >> 6;
  int f = lane & 15, g = lane >> 4;
  int nb = (nt << 7) + (wid << 5);
  const unsigned short* vpv = vp + ((long)(v * 16 + f) << 9);
  for (int h = 0; h < H_; ++h) {
    half8 b0 = *(const half8*)(vpv + h * 64 + (g << 3));
    half8 b1 = *(const half8*)(vpv + h * 64 + 32 + (g << 3));
#pragma unroll
    for (int mf = 0; mf < 2; ++mf) {
      int n = nb + (mf << 4) + f;
      half8 a0 = *(const half8*)(WoT + ((long)n << 9) + h * 64 + (g << 3));
      half8 a1 = *(const half8*)(WoT + ((long)n << 9) + h * 64 + 32 + (g << 3));
      f32x4 acc = {0.f, 0.f, 0.f, 0.f};
      acc = __builtin_amdgcn_mfma_f32_16x16x32_f16(a0, b0, acc, 0, 0, 0);
      acc = __builtin_amdgcn_mfma_f32_16x16x32_f16(a1, b1, acc, 0, 0, 0);
      if (f < F_) {
#pragma unroll
        for (int r = 0; r < 4; ++r) {
          int nr = nb + (mf << 4) + (g << 2) + r;
          Zt[(long)(v * 512 + nr) * 96 + h * 12 + f] = f2h(acc[r]);
        }
      }
    }
  }
}

// ---------------------------------------------------------------------------
// K3: logits + softmax over frames -> Wt[v][t][h*12+f]
// per (v,h, t16): C[t][f] = q-rows x kproj-f-rows; softmax across 16-lane cols
// grid = 512 v * 8 ttiles(64); wave covers 16 t
// ---------------------------------------------------------------------------
__global__ __launch_bounds__(256) void k3_w(char* ws) {
  __shared__ unsigned short Ks[16 * 520];
  int bx = blockIdx.x, tid = threadIdx.x;
  int v = bx >> 3, tt = bx & 7;
  const unsigned short* qb = (const unsigned short*)(ws + OFF_QB);
  const unsigned short* kp = (const unsigned short*)(ws + OFF_KP);
  unsigned short* Wt = (unsigned short*)(ws + OFF_WT);
  const unsigned short* kpv = kp + ((long)v << 13);
#pragma unroll
  for (int j = 0; j < 4; ++j) {
    int flat = (j * 256 + tid) * 8;
    int row = flat >> 9, col = flat & 511;
    uint4v x = *(const uint4v*)(kpv + flat);
    *(uint4v*)(Ks + row * 520 + col) = x;
  }
  __syncthreads();
  int lane = tid & 63, wid = tid >> 6;
  int f = lane & 15, g = lane >> 4;
  int t0 = (tt << 6) + (wid << 4);
  const unsigned short* qrow = qb + ((long)(t0 + f) << 9);
  for (int h = 0; h < H_; ++h) {
    half8 a0 = *(const half8*)(qrow + h * 64 + (g << 3));
    half8 a1 = *(const half8*)(qrow + h * 64 + 32 + (g << 3));
    half8 b0 = *(const half8*)(Ks + f * 520 + h * 64 + (g << 3));
    half8 b1 = *(const half8*)(Ks + f * 520 + h * 64 + 32 + (g << 3));
    f32x4 acc = {0.f, 0.f, 0.f, 0.f};
    acc = __builtin_amdgcn_mfma_f32_16x16x32_f16(a0, b0, acc, 0, 0, 0);
    acc = __builtin_amdgcn_mfma_f32_16x16x32_f16(a1, b1, acc, 0, 0, 0);
#pragma unroll
    for (int r = 0; r < 4; ++r) {
      float x = (f < F_) ? acc[r] : -1e30f;
      float mm = x;
      mm = fmaxf(mm, __shfl_xor(mm, 1, 16));
      mm = fmaxf(mm, __shfl_xor(mm, 2, 16));
      mm = fmaxf(mm, __shfl_xor(mm, 4, 16));
      mm = fmaxf(mm, __shfl_xor(mm, 8, 16));
      float e = (f < F_) ? __expf(x - mm) : 0.0f;
      float ss = e;
      ss += __shfl_xor(ss, 1, 16);
      ss += __shfl_xor(ss, 2, 16);
      ss += __shfl_xor(ss, 4, 16);
      ss += __shfl_xor(ss, 8, 16);
      if (f < F_) {
        int t = t0 + (g << 2) + r;
        Wt[(long)(v * 512 + t) * 96 + h * 12 + f] = f2h(e / ss);
      }
    }
  }
}

// ---------------------------------------------------------------------------
// K4: out[v][t][n] = sum_{hf} Wt[v][t][hf] * Zt-as-B[hf][n] + bo[n]
// per v: [512,96]x[96,512]; block = (v, 128t x 128n), 4 waves 2x2 of 64x64
// ---------------------------------------------------------------------------
__global__ __launch_bounds__(256) void k4_out(char* ws, const float* __restrict__ bo,
                                              float* __restrict__ outp) {
  __shared__ unsigned short As[128 * 104];
  __shared__ unsigned short Bs[128 * 104];
  int bx = blockIdx.x, tid = threadIdx.x;
  int v = bx >> 4, tt = (bx >> 2) & 3, nt = bx & 3;
  const unsigned short* Wt = (const unsigned short*)(ws + OFF_WT);
  const unsigned short* Zt = (const unsigned short*)(ws + OFF_ZT);
  const unsigned short* Asrc = Wt + ((long)v * 512 + tt * 128) * 96;
  const unsigned short* Bsrc = Zt + ((long)v * 512 + nt * 128) * 96;
#pragma unroll
  for (int j = 0; j < 6; ++j) {
    int flat = (j * 256 + tid) * 8;  // 0..12287 ushorts
    int row = flat / 96;
    int col = flat - row * 96;
    uint4v a = *(const uint4v*)(Asrc + flat);
    uint4v b = *(const uint4v*)(Bsrc + flat);
    *(uint4v*)(As + row * 104 + col) = a;
    *(uint4v*)(Bs + row * 104 + col) = b;
  }
  __syncthreads();
  int lane = tid & 63, wid = tid >> 6;
  int g = lane >> 4, l15 = lane & 15;
  int mw = (wid >> 1) << 6, nw = (wid & 1) << 6;
  f32x4 acc[4][4];
#pragma unroll
  for (int i = 0; i < 4; i++)
#pragma unroll
    for (int j = 0; j < 4; j++) acc[i][j] = (f32x4){0.f, 0.f, 0.f, 0.f};
#pragma unroll
  for (int ks = 0; ks < 3; ++ks) {
    half8 a[4], b[4];
#pragma unroll
    for (int i = 0; i < 4; i++) {
      a[i] = *(const half8*)(As + (mw + i * 16 + l15) * 104 + ks * 32 + (g << 3));
      b[i] = *(const half8*)(Bs + (nw + i * 16 + l15) * 104 + ks * 32 + (g << 3));
    }
#pragma unroll
    for (int i = 0; i < 4; i++)
#pragma unroll
      for (int j = 0; j < 4; j++)
        acc[i][j] = __builtin_amdgcn_mfma_f32_16x16x32_f16(a[i], b[j], acc[i][j], 0, 0, 0);
  }
#pragma unroll
  for (int j = 0; j < 4; j++) {
    int n = (nt << 7) + nw + j * 16 + l15;
    float bias = bo[n];
#pragma unroll
    for (int i = 0; i < 4; i++) {
      long tb_ = (long)(v * 512 + (tt << 7) + mw + i * 16 + (g << 2));
#pragma unroll
      for (int r = 0; r < 4; r++) {
        outp[(tb_ + r) * 512 + n] = acc[i][j][r] + bias;
      }
    }
  }
}

extern "C" void kernel_launch(void* const* d_in, const int* in_sizes, int n_in,
                              void* d_out, int out_size, void* d_ws, size_t ws_size,
                              hipStream_t stream) {
  const float* text  = (const float*)d_in[0];
  const float* video = (const float*)d_in[1];
  const float* Wq = (const float*)d_in[2];
  const float* bq = (const float*)d_in[3];
  const float* Wk = (const float*)d_in[4];
  const float* bk = (const float*)d_in[5];
  const float* Wv = (const float*)d_in[6];
  const float* bv = (const float*)d_in[7];
  const float* Wo = (const float*)d_in[8];
  const float* bo = (const float*)d_in[9];
  char* ws = (char*)d_ws;
  float* out = (float*)d_out;

  k0_prep<<<dim3(2432), dim3(256), 0, stream>>>(text, video, Wq, Wk, Wv, Wo, ws);
  k1_proj<<<dim3(528), dim3(256), 0, stream>>>(ws, bq, bk, bv);
  k2_z<<<dim3(2048), dim3(256), 0, stream>>>(ws);
  k3_w<<<dim3(4096), dim3(256), 0, stream>>>(ws);
  k4_out<<<dim3(8192), dim3(256), 0, stream>>>(ws, bo, out);
}